// Round 3
// baseline (301.442 us; speedup 1.0000x reference)
//
#include <hip/hip_runtime.h>
#include <hip/hip_bf16.h>

// CDC conv: out = conv3x3(x,W,zero-pad) + b - 0.7 * laplacian(channel_sum(x), edge-pad)
// bf16 MFMA implicit GEMM (9 tap-GEMMs, K=Cin), fp32 stencil epilogue.
// Round 3: W tile double-buffered (prefetch next tap before MFMAs), 1 barrier/tap
// instead of 2, diffs/bias moved out of LDS -> exactly 80KB LDS = 2 blocks/CU.
// ws layout: [0,128MB) x_t bf16 [b][h][w][ci] (chunk-swizzled), [128MB,+288KB) W_packed
// [tap][co][ci] bf16 (swizzled), then s[b][h][w] f32 (8MB).

typedef __attribute__((ext_vector_type(8))) short short8;
typedef __attribute__((ext_vector_type(4))) float f32x4;

#define THETA 0.7f
#define XT_OFF   0
#define WP_OFF   134217728ull          // 32*128*128*128*2
#define S_OFF    (134217728ull + 294912ull)

__device__ __forceinline__ unsigned short f2b(float f) {
  unsigned u = __builtin_bit_cast(unsigned, f);
  u += 0x7FFFu + ((u >> 16) & 1u);     // RNE
  return (unsigned short)(u >> 16);
}

__device__ __forceinline__ void gload_lds16(const void* g, void* l) {
  __builtin_amdgcn_global_load_lds(
      (const __attribute__((address_space(1))) unsigned int*)g,
      (__attribute__((address_space(3))) unsigned int*)l, 16, 0, 0);
}

// ---- pack W[co][ci][3][3] f32 -> wp[tap][co][ci] bf16, XOR-swizzled per co row
__global__ void pack_w_kernel(const float* __restrict__ w, char* __restrict__ wp) {
  const int co = blockIdx.x, ci = threadIdx.x;
  const float* src = w + ((size_t)co * 128 + ci) * 9;
  #pragma unroll
  for (int tap = 0; tap < 9; ++tap) {
    const unsigned short bv = f2b(src[tap]);
    const int off = tap * 32768 + co * 256 + ((ci * 2) ^ ((co & 7) << 4));
    *(unsigned short*)(wp + off) = bv;
  }
}

// ---- x[b][ci][h][w] f32 -> x_t[b][h][w][ci] bf16 (swizzled) + s[b][h][w] = sum_ci x
__global__ __launch_bounds__(256)
void transpose_sum_kernel(const float* __restrict__ x, char* __restrict__ xt,
                          float* __restrict__ s) {
  __shared__ float tile[128][129];
  __shared__ float s2[2][128];
  const int h = blockIdx.x, b = blockIdx.y;
  const int t = threadIdx.x;
  {
    const int ciq = t >> 5;              // 0..7
    const int wq = (t & 31) << 2;        // 0..124
    #pragma unroll
    for (int i = 0; i < 16; ++i) {
      const int ci = i * 8 + ciq;
      const float4 v = *(const float4*)(x + (((size_t)(b * 128 + ci) * 128 + h) * 128 + wq));
      tile[ci][wq] = v.x; tile[ci][wq + 1] = v.y;
      tile[ci][wq + 2] = v.z; tile[ci][wq + 3] = v.w;
    }
  }
  __syncthreads();
  {
    const int w = t & 127, p = t >> 7;
    float acc = 0.f;
    #pragma unroll 8
    for (int j = 0; j < 64; ++j) acc += tile[p * 64 + j][w];
    s2[p][w] = acc;
  }
  char* rowb = xt + (size_t)(b * 128 + h) * 32768;
  // 128 w * 16 chunks(16B) = 2048 chunks; 256 threads -> 8 iters
  #pragma unroll
  for (int i = 0; i < 8; ++i) {
    const int u = i * 256 + t;           // 0..2047 chunk id
    const int w = u >> 4, chunk = u & 15;
    const int ci0 = chunk * 8;
    short8 o;
    #pragma unroll
    for (int j = 0; j < 8; ++j) o[j] = (short)f2b(tile[ci0 + j][w]);
    *(short8*)(rowb + w * 256 + ((chunk ^ (w & 7)) * 16)) = o;
  }
  __syncthreads();
  if (t < 128) s[(size_t)(b * 128 + h) * 128 + t] = s2[0][t] + s2[1][t];
}

// ---- conv: block=(h,b); 4 waves; wave = 64co x 64pix; K = 18 ktiles of 64
__global__ __launch_bounds__(256, 2)
void conv_mfma_kernel(const char* __restrict__ xt, const char* __restrict__ wp,
                      const float* __restrict__ bias, const float* __restrict__ s,
                      float* __restrict__ out) {
  __shared__ uint4 xs4[3 * 1024];   // 48KB: 3 rows * 128w * 64ci bf16
  __shared__ uint4 wt4[2][1024];    // 32KB: double-buffered 128co * 64ci bf16
  char* xs = (char*)xs4;            // total 80KB exactly -> 2 blocks/CU

  const int h = blockIdx.x, b = blockIdx.y;
  const int t = threadIdx.x;
  const int lane = t & 63, wave = t >> 6;
  const int wm = wave >> 1, wn = wave & 1;
  const int l15 = lane & 15, lg = lane >> 4;

  f32x4 acc[4][4];
  #pragma unroll
  for (int m = 0; m < 4; ++m)
    #pragma unroll
    for (int n = 0; n < 4; ++n)
      acc[m][n] = (f32x4){0.f, 0.f, 0.f, 0.f};

  auto stage_x = [&](int cih) {
    #pragma unroll
    for (int r = 0; r < 3; ++r) {  // rows h-1..h+1, zero-pad out of range
      const int hh = h - 1 + r;
      if ((unsigned)hh < 128u) {
        const char* rb = xt + ((size_t)(b * 128 + hh) * 32768 + cih * 128);
        #pragma unroll
        for (int i = 0; i < 4; ++i) {
          const int u = i * 256 + t;
          gload_lds16(rb + (size_t)(u >> 3) * 256 + (u & 7) * 16,
                      xs + r * 16384 + u * 16);
        }
      } else {
        #pragma unroll
        for (int i = 0; i < 4; ++i) {
          const int u = i * 256 + t;
          *(uint4*)(xs + r * 16384 + u * 16) = make_uint4(0u, 0u, 0u, 0u);
        }
      }
    }
  };
  auto stage_w = [&](int kt, int buf) {
    const int cih = (kt >= 9) ? 1 : 0;
    const int tap = kt - cih * 9;
    const char* rb = wp + ((size_t)tap * 32768 + cih * 128);
    char* dst = (char*)wt4[buf];
    #pragma unroll
    for (int i = 0; i < 4; ++i) {
      const int u = i * 256 + t;
      gload_lds16(rb + (size_t)(u >> 3) * 256 + (u & 7) * 16, dst + u * 16);
    }
  };

  stage_x(0);
  stage_w(0, 0);
  __syncthreads();                 // drain prologue stages

  int p = 0;
  for (int kt = 0; kt < 18; ++kt) {
    const int tap = (kt >= 9) ? kt - 9 : kt;
    if (kt == 9) {                 // end-of-kt8 barrier freed xs; restage ci half 1
      stage_x(1);
      __syncthreads();
    }
    if (kt < 17) stage_w(kt + 1, p ^ 1);  // prefetch: drains at END-of-tap barrier
    const int kh = tap / 3;
    const int dx = tap - kh * 3 - 1;
    const char* xrow = xs + kh * 16384;
    const char* wt = (const char*)wt4[p];
    #pragma unroll
    for (int kk = 0; kk < 2; ++kk) {
      short8 af[4];
      #pragma unroll
      for (int m = 0; m < 4; ++m) {
        const int co = wm * 64 + m * 16 + l15;
        const int phys = (kk * 4 + lg) ^ (co & 7);
        af[m] = *(const short8*)(wt + co * 128 + phys * 16);
      }
      short8 bf[4];
      #pragma unroll
      for (int n = 0; n < 4; ++n) {
        const int wsrc = wn * 64 + n * 16 + l15 + dx;
        short8 v = {0, 0, 0, 0, 0, 0, 0, 0};
        if ((unsigned)wsrc < 128u) {
          const int phys = (kk * 4 + lg) ^ (wsrc & 7);
          v = *(const short8*)(xrow + wsrc * 128 + phys * 16);
        }
        bf[n] = v;
      }
      #pragma unroll
      for (int m = 0; m < 4; ++m)
        #pragma unroll
        for (int n = 0; n < 4; ++n)
          acc[m][n] = __builtin_amdgcn_mfma_f32_16x16x32_bf16(af[m], bf[n], acc[m][n], 0, 0, 0);
    }
    __syncthreads();               // readers done with wt4[p] + prefetch landed
    p ^= 1;
  }

  // epilogue: per-thread fp32 stencil from s (L3-resident) + bias (L2)
  const float* sb = s + (size_t)b * 16384;
  float dif[4];
  #pragma unroll
  for (int n = 0; n < 4; ++n) {
    const int w = wn * 64 + n * 16 + l15;
    const float sc = sb[h * 128 + w];
    const float up = sb[(h > 0 ? h - 1 : 0) * 128 + w];
    const float dn = sb[(h < 127 ? h + 1 : 127) * 128 + w];
    const float lf = sb[h * 128 + (w > 0 ? w - 1 : 0)];
    const float rt = sb[h * 128 + (w < 127 ? w + 1 : 127)];
    dif[n] = up + dn + lf + rt - 4.0f * sc;
  }
  // C/D layout (verified m89): col=lane&15 (=pix), row=(lane>>4)*4+reg (=co)
  #pragma unroll
  for (int m = 0; m < 4; ++m) {
    #pragma unroll
    for (int r = 0; r < 4; ++r) {
      const int co = wm * 64 + m * 16 + lg * 4 + r;
      const float bv = bias[co];
      float* orow = out + ((size_t)(b * 128 + co) * 128 + h) * 128;
      #pragma unroll
      for (int n = 0; n < 4; ++n) {
        const int w = wn * 64 + n * 16 + l15;
        orow[w] = acc[m][n][r] + bv - THETA * dif[n];
      }
    }
  }
}

extern "C" void kernel_launch(void* const* d_in, const int* in_sizes, int n_in,
                              void* d_out, int out_size, void* d_ws, size_t ws_size,
                              hipStream_t stream) {
  const float* x = (const float*)d_in[0];
  const float* W = (const float*)d_in[1];
  const float* bias = (const float*)d_in[2];
  float* out = (float*)d_out;
  char* ws = (char*)d_ws;
  char* xt = ws + XT_OFF;
  char* wp = ws + WP_OFF;
  float* s = (float*)(ws + S_OFF);
  // needs ~142,901,248 bytes of ws
  pack_w_kernel<<<dim3(128), dim3(128), 0, stream>>>(W, wp);
  transpose_sum_kernel<<<dim3(128, 32), dim3(256), 0, stream>>>(x, xt, s);
  conv_mfma_kernel<<<dim3(128, 32), dim3(256), 0, stream>>>(xt, wp, bias, s, out);
}

// Round 4
// 279.806 us; speedup vs baseline: 1.0773x; 1.0773x over previous
//
#include <hip/hip_runtime.h>
#include <hip/hip_bf16.h>

// CDC conv: out = conv3x3(x,W,zero-pad) + b - 0.7 * laplacian(channel_sum(x), edge-pad)
// bf16 MFMA implicit GEMM (9 tap-GEMMs, K=Cin), fp32 stencil epilogue.
// Round 4: W fragments loaded straight from global (L2-resident 288KB) into
// registers -> no W LDS, no per-tap barriers (3 __syncthreads/block total).
// LDS 48KB -> 3 blocks/CU (3 waves/SIMD).
// ws layout: [0,128MB) x_t bf16 [b][h][w][ci] (chunk-swizzled),
// [128MB,+288KB) W_packed [tap][kchunk:16][co:128][8ci] bf16 (linear),
// then s[b][h][w] f32 (8MB).

typedef __attribute__((ext_vector_type(8))) short short8;
typedef __attribute__((ext_vector_type(4))) float f32x4;

#define THETA 0.7f
#define XT_OFF   0
#define WP_OFF   134217728ull          // 32*128*128*128*2
#define S_OFF    (134217728ull + 294912ull)

__device__ __forceinline__ unsigned short f2b(float f) {
  unsigned u = __builtin_bit_cast(unsigned, f);
  u += 0x7FFFu + ((u >> 16) & 1u);     // RNE
  return (unsigned short)(u >> 16);
}

__device__ __forceinline__ void gload_lds16(const void* g, void* l) {
  __builtin_amdgcn_global_load_lds(
      (const __attribute__((address_space(1))) unsigned int*)g,
      (__attribute__((address_space(3))) unsigned int*)l, 16, 0, 0);
}

// ---- pack W[co][ci][3][3] f32 -> wp[tap][c:16][co:128][8] bf16 (linear)
__global__ void pack_w_kernel(const float* __restrict__ w, char* __restrict__ wp) {
  const int co = blockIdx.x, ci = threadIdx.x;
  const float* src = w + ((size_t)co * 128 + ci) * 9;
  const int c = ci >> 3, j = ci & 7;
  #pragma unroll
  for (int tap = 0; tap < 9; ++tap) {
    const unsigned short bv = f2b(src[tap]);
    *(unsigned short*)(wp + (((size_t)(tap * 16 + c) * 128 + co) * 16 + j * 2)) = bv;
  }
}

// ---- x[b][ci][h][w] f32 -> x_t[b][h][w][ci] bf16 (swizzled) + s[b][h][w] = sum_ci x
__global__ __launch_bounds__(256)
void transpose_sum_kernel(const float* __restrict__ x, char* __restrict__ xt,
                          float* __restrict__ s) {
  __shared__ float tile[128][129];
  __shared__ float s2[2][128];
  const int h = blockIdx.x, b = blockIdx.y;
  const int t = threadIdx.x;
  {
    const int ciq = t >> 5;              // 0..7
    const int wq = (t & 31) << 2;        // 0..124
    #pragma unroll
    for (int i = 0; i < 16; ++i) {
      const int ci = i * 8 + ciq;
      const float4 v = *(const float4*)(x + (((size_t)(b * 128 + ci) * 128 + h) * 128 + wq));
      tile[ci][wq] = v.x; tile[ci][wq + 1] = v.y;
      tile[ci][wq + 2] = v.z; tile[ci][wq + 3] = v.w;
    }
  }
  __syncthreads();
  {
    const int w = t & 127, p = t >> 7;
    float acc = 0.f;
    #pragma unroll 8
    for (int j = 0; j < 64; ++j) acc += tile[p * 64 + j][w];
    s2[p][w] = acc;
  }
  char* rowb = xt + (size_t)(b * 128 + h) * 32768;
  // 128 w * 16 chunks(16B) = 2048 chunks; 256 threads -> 8 iters
  #pragma unroll
  for (int i = 0; i < 8; ++i) {
    const int u = i * 256 + t;           // 0..2047 chunk id
    const int w = u >> 4, chunk = u & 15;
    const int ci0 = chunk * 8;
    short8 o;
    #pragma unroll
    for (int j = 0; j < 8; ++j) o[j] = (short)f2b(tile[ci0 + j][w]);
    *(short8*)(rowb + w * 256 + ((chunk ^ (w & 7)) * 16)) = o;
  }
  __syncthreads();
  if (t < 128) s[(size_t)(b * 128 + h) * 128 + t] = s2[0][t] + s2[1][t];
}

// ---- conv: block=(h,b); 4 waves; wave = 64co x 64pix; W from global->regs
__global__ __launch_bounds__(256, 3)
void conv_mfma_kernel(const char* __restrict__ xt, const char* __restrict__ wp,
                      const float* __restrict__ bias, const float* __restrict__ s,
                      float* __restrict__ out) {
  __shared__ uint4 xs4[3 * 1024];   // 48KB: 3 rows * 128w * 64ci bf16
  char* xs = (char*)xs4;

  const int h = blockIdx.x, b = blockIdx.y;
  const int t = threadIdx.x;
  const int lane = t & 63, wave = t >> 6;
  const int wm = wave >> 1, wn = wave & 1;
  const int l15 = lane & 15, lg = lane >> 4;

  f32x4 acc[4][4];
  #pragma unroll
  for (int m = 0; m < 4; ++m)
    #pragma unroll
    for (int n = 0; n < 4; ++n)
      acc[m][n] = (f32x4){0.f, 0.f, 0.f, 0.f};

  auto stage_x = [&](int cih) {
    #pragma unroll
    for (int r = 0; r < 3; ++r) {  // rows h-1..h+1, zero-pad out of range
      const int hh = h - 1 + r;
      if ((unsigned)hh < 128u) {
        const char* rb = xt + ((size_t)(b * 128 + hh) * 32768 + cih * 128);
        #pragma unroll
        for (int i = 0; i < 4; ++i) {
          const int u = i * 256 + t;
          gload_lds16(rb + (size_t)(u >> 3) * 256 + (u & 7) * 16,
                      xs + r * 16384 + u * 16);
        }
      } else {
        #pragma unroll
        for (int i = 0; i < 4; ++i) {
          const int u = i * 256 + t;
          *(uint4*)(xs + r * 16384 + u * 16) = make_uint4(0u, 0u, 0u, 0u);
        }
      }
    }
  };

  auto compute_half = [&](int khalf) {
    #pragma unroll
    for (int kh = 0; kh < 3; ++kh) {
      const char* xrow = xs + kh * 16384;
      #pragma unroll
      for (int dxi = 0; dxi < 3; ++dxi) {
        const int tap = kh * 3 + dxi;
        const int dx = dxi - 1;
        // A-fragments direct from global (L2-resident), coalesced 256B runs
        const char* wb = wp + (size_t)(tap * 16 + khalf * 8) * 2048;
        short8 af[2][4];
        #pragma unroll
        for (int kk = 0; kk < 2; ++kk)
          #pragma unroll
          for (int m = 0; m < 4; ++m)
            af[kk][m] = *(const short8*)(wb + (kk * 4 + lg) * 2048 +
                                         (wm * 64 + m * 16 + l15) * 16);
        #pragma unroll
        for (int kk = 0; kk < 2; ++kk) {
          short8 bf[4];
          #pragma unroll
          for (int n = 0; n < 4; ++n) {
            const int wsrc = wn * 64 + n * 16 + l15 + dx;
            short8 v = {0, 0, 0, 0, 0, 0, 0, 0};
            if ((unsigned)wsrc < 128u) {
              const int phys = (kk * 4 + lg) ^ (wsrc & 7);
              v = *(const short8*)(xrow + wsrc * 128 + phys * 16);
            }
            bf[n] = v;
          }
          #pragma unroll
          for (int m = 0; m < 4; ++m)
            #pragma unroll
            for (int n = 0; n < 4; ++n)
              acc[m][n] = __builtin_amdgcn_mfma_f32_16x16x32_bf16(af[kk][m], bf[n], acc[m][n], 0, 0, 0);
        }
      }
    }
  };

  stage_x(0);
  __syncthreads();                 // xs half-0 ready
  compute_half(0);
  __syncthreads();                 // all waves done reading xs half-0
  stage_x(1);
  __syncthreads();                 // xs half-1 ready
  compute_half(1);

  // epilogue: per-thread fp32 stencil from s (L3-resident) + bias (L2)
  const float* sb = s + (size_t)b * 16384;
  float dif[4];
  #pragma unroll
  for (int n = 0; n < 4; ++n) {
    const int w = wn * 64 + n * 16 + l15;
    const float sc = sb[h * 128 + w];
    const float up = sb[(h > 0 ? h - 1 : 0) * 128 + w];
    const float dn = sb[(h < 127 ? h + 1 : 127) * 128 + w];
    const float lf = sb[h * 128 + (w > 0 ? w - 1 : 0)];
    const float rt = sb[h * 128 + (w < 127 ? w + 1 : 127)];
    dif[n] = up + dn + lf + rt - 4.0f * sc;
  }
  // C/D layout (verified m89): col=lane&15 (=pix), row=(lane>>4)*4+reg (=co)
  #pragma unroll
  for (int m = 0; m < 4; ++m) {
    #pragma unroll
    for (int r = 0; r < 4; ++r) {
      const int co = wm * 64 + m * 16 + lg * 4 + r;
      const float bv = bias[co];
      float* orow = out + ((size_t)(b * 128 + co) * 128 + h) * 128;
      #pragma unroll
      for (int n = 0; n < 4; ++n) {
        const int w = wn * 64 + n * 16 + l15;
        orow[w] = acc[m][n][r] + bv - THETA * dif[n];
      }
    }
  }
}

extern "C" void kernel_launch(void* const* d_in, const int* in_sizes, int n_in,
                              void* d_out, int out_size, void* d_ws, size_t ws_size,
                              hipStream_t stream) {
  const float* x = (const float*)d_in[0];
  const float* W = (const float*)d_in[1];
  const float* bias = (const float*)d_in[2];
  float* out = (float*)d_out;
  char* ws = (char*)d_ws;
  char* xt = ws + XT_OFF;
  char* wp = ws + WP_OFF;
  float* s = (float*)(ws + S_OFF);
  // needs ~142,901,248 bytes of ws
  pack_w_kernel<<<dim3(128), dim3(128), 0, stream>>>(W, wp);
  transpose_sum_kernel<<<dim3(128, 32), dim3(256), 0, stream>>>(x, xt, s);
  conv_mfma_kernel<<<dim3(128, 32), dim3(256), 0, stream>>>(xt, wp, bias, s, out);
}